// Round 4
// baseline (351.690 us; speedup 1.0000x reference)
//
#include <hip/hip_runtime.h>

// Problem constants from setup_inputs(): B=8, N=8192, D=512, fp32 in/out.
#define DIM 512
#define NPB 8192          // rows per batch (N)
#define NBLK 1024
#define TPB 256
#define NWAVES (NBLK * TPB / 64)   // 4096 persistent waves
#define RPI 2             // rows per iteration per wave

typedef float f4 __attribute__((ext_vector_type(4)));

__device__ __forceinline__ float dot4(f4 u, f4 v) {
    f4 p = u * v;
    return p.x + p.y + p.z + p.w;
}

// R3: persistent waves + REAL software pipeline.
// Evidence from R1/R2: R1's "pipelined" kernel reported VGPR_Count=40, but a
// live 1-row lookahead needs >=48 VGPRs -> the compiler sank the prefetch
// loads below the shuffle reduction, so every row paid full loaded-HBM
// latency with zero loads outstanding during the ~1000-cyc reduce tail.
// Here: 2 rows/iter, prefetch next 2 rows, then sched_barrier(0) pins the
// loads ABOVE the compute/reduce so 12 KB/wave stays in flight continuously.
// Mapping stays dense: iteration `it` covers exactly batch `it` (rows
// it*8192 + wid*2 + {0,1}), all 4096 waves sweeping one contiguous band.
__global__ __launch_bounds__(TPB, 4) void disc_kernel(
    const float* __restrict__ s,
    const float* __restrict__ hrl,
    const float* __restrict__ hfk,
    float* __restrict__ out,
    int n_rows) {
    int wid  = (blockIdx.x * blockDim.x + threadIdx.x) >> 6;
    int lane = threadIdx.x & 63;

    const int iters = n_rows / (NWAVES * RPI);   // 8 for the bench shape

    // float offset of this wave's row-pair at iteration it:
    //   base(it) = (it*NWAVES + wid) * RPI * DIM
    size_t base = (size_t)wid * RPI * DIM;
    const size_t step = (size_t)NWAVES * RPI * DIM;

    f4 cur[12], nxt[12];

    // Row-pair loader: 12 x 1KB coalesced dwordx4 loads.
    //   [0..5]  = row0 {s,a,b} x {lo,hi},  [6..11] = row1.
    auto load_pair = [&](size_t b, f4* dst) {
        const f4* sp = (const f4*)(s   + b);
        const f4* ap = (const f4*)(hrl + b);
        const f4* bp = (const f4*)(hfk + b);
        dst[0]  = sp[lane];       dst[1]  = sp[lane + 64];
        dst[2]  = ap[lane];       dst[3]  = ap[lane + 64];
        dst[4]  = bp[lane];       dst[5]  = bp[lane + 64];
        dst[6]  = sp[lane + 128]; dst[7]  = sp[lane + 192];
        dst[8]  = ap[lane + 128]; dst[9]  = ap[lane + 192];
        dst[10] = bp[lane + 128]; dst[11] = bp[lane + 192];
    };

    load_pair(base, cur);

    for (int it = 0; it < iters; ++it) {
        // Issue next iteration's 12 loads BEFORE the compute/reduce...
        if (it + 1 < iters) {
            load_pair(base + step, nxt);
        }
        // ...and forbid the scheduler from sinking them below it.
        __builtin_amdgcn_sched_barrier(0);

        float v[10];
        // row 0
        v[0] = dot4(cur[0], cur[0]) + dot4(cur[1], cur[1]);   // ss
        v[1] = dot4(cur[2], cur[2]) + dot4(cur[3], cur[3]);   // aa
        v[2] = dot4(cur[4], cur[4]) + dot4(cur[5], cur[5]);   // bb
        v[3] = dot4(cur[0], cur[2]) + dot4(cur[1], cur[3]);   // sa
        v[4] = dot4(cur[0], cur[4]) + dot4(cur[1], cur[5]);   // sb
        // row 1
        v[5] = dot4(cur[6], cur[6])  + dot4(cur[7], cur[7]);
        v[6] = dot4(cur[8], cur[8])  + dot4(cur[9], cur[9]);
        v[7] = dot4(cur[10], cur[10]) + dot4(cur[11], cur[11]);
        v[8] = dot4(cur[6], cur[8])  + dot4(cur[7], cur[9]);
        v[9] = dot4(cur[6], cur[10]) + dot4(cur[7], cur[11]);

        // 10 independent butterfly chains, interleaved in the DS pipe.
        #pragma unroll
        for (int off = 32; off > 0; off >>= 1) {
            #pragma unroll
            for (int k = 0; k < 10; ++k) v[k] += __shfl_xor(v[k], off, 64);
        }

        if (lane == 0) {
            const float eps = 1e-12f;
            int row0 = (int)(base / DIM);        // = it*8192 + wid*2
            int bidx = row0 >> 13;
            int n0   = row0 & (NPB - 1);
            size_t obase = (size_t)bidx * (2 * NPB) + n0;

            float ns0 = fmaxf(sqrtf(v[0]), eps);
            float na0 = fmaxf(sqrtf(v[1]), eps);
            float nb0 = fmaxf(sqrtf(v[2]), eps);
            out[obase]           = v[3] / (ns0 * na0);
            out[obase + NPB]     = v[4] / (ns0 * nb0);

            float ns1 = fmaxf(sqrtf(v[5]), eps);
            float na1 = fmaxf(sqrtf(v[6]), eps);
            float nb1 = fmaxf(sqrtf(v[7]), eps);
            out[obase + 1]       = v[8] / (ns1 * na1);
            out[obase + NPB + 1] = v[9] / (ns1 * nb1);
        }

        // Rotate pipeline registers (full unroll -> pure register renaming).
        #pragma unroll
        for (int k = 0; k < 12; ++k) cur[k] = nxt[k];
        base += step;
    }
}

extern "C" void kernel_launch(void* const* d_in, const int* in_sizes, int n_in,
                              void* d_out, int out_size, void* d_ws, size_t ws_size,
                              hipStream_t stream) {
    const float* s   = (const float*)d_in[0];
    const float* hrl = (const float*)d_in[1];
    const float* hfk = (const float*)d_in[2];
    float* out = (float*)d_out;

    int n_rows = in_sizes[0] / DIM;            // B*N = 65536
    disc_kernel<<<NBLK, TPB, 0, stream>>>(s, hrl, hfk, out, n_rows);
}